// Round 17
// baseline (133.702 us; speedup 1.0000x reference)
//
#include <hip/hip_runtime.h>
#include <stdint.h>

#define KSTEPS 24              // 768 / 32
#define TOKENS 16384           // B*S

typedef short short8 __attribute__((ext_vector_type(8)));
typedef float fx4 __attribute__((ext_vector_type(4)));
typedef unsigned short u16;
typedef u16 u16x4 __attribute__((ext_vector_type(4)));
typedef u16 u16x8 __attribute__((ext_vector_type(8)));

static __device__ __forceinline__ u16 f2bf(float f) {
  union { float f; unsigned u; } v; v.f = f;
  return (u16)((v.u + 0x7fffu + ((v.u >> 16) & 1u)) >> 16);
}

// cheap round (half-up): used post-exp2 / on partials, tolerance-safe
static __device__ __forceinline__ u16 p2bf(float f) {
  union { float f; unsigned u; } v; v.f = f;
  return (u16)((v.u + 0x8000u) >> 16);
}

static __device__ __forceinline__ float bf2f(u16 h) {
  union { unsigned u; float f; } v; v.u = ((unsigned)h) << 16;
  return v.f;
}

static __device__ __forceinline__ fx4 mfma16(short8 a, short8 b, fx4 c) {
  return __builtin_amdgcn_mfma_f32_16x16x32_bf16(a, b, c, 0, 0, 0);
}

// async global->LDS, 16B/lane; lds dest = wave-uniform base + lane*16
static __device__ __forceinline__ void async16(const void* g, void* l) {
  __builtin_amdgcn_global_load_lds(
      (const __attribute__((address_space(1))) void*)g,
      (__attribute__((address_space(3))) void*)(unsigned int)(uintptr_t)l,
      16, 0, 0);
}

// ---------------- prep: W[768][64] fp32 (q,k,v) -> bf16 pre-fragmented B-operand layout
__global__ void prep_w_kernel(const float* __restrict__ Wq, const float* __restrict__ Wk,
                              const float* __restrict__ Wv, u16* __restrict__ wfrag) {
  int idx  = blockIdx.x * 256 + threadIdx.x;   // 72*256 = 18432 = 3*24*4*64
  int lane = idx & 63;
  int fid  = idx >> 6;
  int nt   = fid & 3;
  int ks   = (fid >> 2) % KSTEPS;
  int mat  = fid / (KSTEPS * 4);
  const float* W = (mat == 0) ? Wq : (mat == 1) ? Wk : Wv;
  int n  = nt * 16 + (lane & 15);
  int k0 = ks * 32 + (lane >> 4) * 8;
  short8 out;
#pragma unroll
  for (int j = 0; j < 8; j++) out[j] = (short)f2bf(W[(size_t)(k0 + j) * 64 + n]);
  *(short8*)(wfrag + (size_t)idx * 8) = out;
}

// ---------------- projection GEMM v6: 64 tok/block, BK=32, LDS-staged dbuf.
// LDS 40KB -> 4 blocks/CU = 16 waves/CU; W DMA halved vs 32-tok (amortized over
// 64 tokens); each B-frag ds_read feeds 2 MFMAs (two 16-row tiles per wave).
__global__ __launch_bounds__(256) void proj_kernel(const float* __restrict__ x,
                                                   const u16* __restrict__ wfrag,
                                                   u16* __restrict__ qb,
                                                   u16* __restrict__ kb,
                                                   u16* __restrict__ vT) {
  __shared__ float xs[2][64 * 32];    // [dbuf][tok][32 floats] chunk-swizzled, 8KB
  __shared__ u16  Ws[2][12 * 512];    // [dbuf][m*4+nt][lane][8], 12KB

  int w = threadIdx.x >> 6, lane = threadIdx.x & 63;
  int ln = lane & 15, quad = lane >> 4;
  int rw = w >> 1, cs = w & 1;
  int s0 = blockIdx.x * 64;

  fx4 acc[2][6];
#pragma unroll
  for (int rt = 0; rt < 2; rt++)
#pragma unroll
    for (int j = 0; j < 6; j++) acc[rt][j] = (fx4){0.f, 0.f, 0.f, 0.f};

#define STAGE_X(ks, buf)                                                       \
  {                                                                            \
    _Pragma("unroll")                                                          \
    for (int j = 0; j < 2; j++) {                                              \
      int cc = (w * 2 + j) * 64 + lane;                                        \
      int row = cc >> 3, c = cc & 7, sc = c ^ (row & 7);                       \
      async16(x + (size_t)(s0 + row) * 768 + (ks) * 32 + sc * 4,               \
              (char*)xs[buf] + cc * 16);                                       \
    }                                                                          \
  }
#define STAGE_W(ks, buf)                                                       \
  {                                                                            \
    _Pragma("unroll")                                                          \
    for (int m = 0; m < 3; m++)                                                \
      async16(wfrag + ((size_t)(m * KSTEPS + (ks)) * 256 + w * 64 + lane) * 8, \
              (char*)Ws[buf] + (m * 4 + w) * 1024 + lane * 16);                \
  }

  STAGE_X(0, 0);
  STAGE_W(0, 0);

  for (int ks = 0; ks < KSTEPS; ks++) {
    __syncthreads();                  // publishes buf ks&1
    if (ks < KSTEPS - 1) {
      int nb = (ks + 1) & 1;
      STAGE_X(ks + 1, nb);
      STAGE_W(ks + 1, nb);
    }
    const float* xb = xs[ks & 1];
    const u16*  wb = Ws[ks & 1];
    short8 af[2];
#pragma unroll
    for (int rt = 0; rt < 2; rt++) {
      int r = rw * 32 + rt * 16 + ln;
      int sl0 = (2 * quad) ^ (r & 7);
      int sl1 = (2 * quad + 1) ^ (r & 7);
      fx4 xa = *(const fx4*)(xb + r * 32 + sl0 * 4);
      fx4 xv = *(const fx4*)(xb + r * 32 + sl1 * 4);
#pragma unroll
      for (int j = 0; j < 4; j++) {
        af[rt][j] = (short)f2bf(xa[j]);
        af[rt][4 + j] = (short)f2bf(xv[j]);
      }
    }
#pragma unroll
    for (int j = 0; j < 6; j++) {
      short8 bf = *(const short8*)(wb + (cs * 6 + j) * 512 + lane * 8);
      acc[0][j] = mfma16(af[0], bf, acc[0][j]);
      acc[1][j] = mfma16(af[1], bf, acc[1][j]);
    }
  }
#undef STAGE_X
#undef STAGE_W

  // epilogue: C/D layout col = lane&15, row = quad*4 + reg; two row-tiles
#pragma unroll
  for (int rt = 0; rt < 2; rt++) {
    int tok0 = s0 + rw * 32 + rt * 16 + quad * 4;
#pragma unroll
    for (int j = 0; j < 6; j++) {
      int f = cs * 6 + j;
      int d = (f & 3) * 16 + ln;
      if (f < 4) {
        // Q pre-scaled by 0.125 * log2(e): scores land in exp2 domain
#pragma unroll
        for (int reg = 0; reg < 4; reg++)
          qb[(size_t)(tok0 + reg) * 64 + d] = f2bf(acc[rt][j][reg] * 0.180336887f);
      } else if (f < 8) {
#pragma unroll
        for (int reg = 0; reg < 4; reg++)
          kb[(size_t)(tok0 + reg) * 64 + d] = f2bf(acc[rt][j][reg]);
      } else {
        int b = tok0 >> 12, s = tok0 & 4095;
        u16x4 vp;
#pragma unroll
        for (int reg = 0; reg < 4; reg++) vp[reg] = f2bf(acc[rt][j][reg]);
        *(u16x4*)(vT + ((size_t)b * 64 + d) * 4096 + s) = vp;
      }
    }
  }
}

// ---------------- flash attention v9b: 32 Q-rows/wave, K+V DMA-staged dbuf,
// split-K 6-way; partials written as BF16 (halves merge traffic).
__global__ __launch_bounds__(256, 3) void attn_kernel(const u16* __restrict__ qb,
                                                      const u16* __restrict__ kb,
                                                      const u16* __restrict__ vT,
                                                      u16* __restrict__ pob,
                                                      float* __restrict__ mlb) {
  __shared__ u16 Kstg[2][4096];       // [buf][64 keys x 64 d]   16KB
  __shared__ u16 Vstg[2][4096];       // [buf][64 d x 64 keys]   16KB (V^T)
  __shared__ u16 Ps[4][32 * 72];      // per-wave P (32 rows), padded: 18KB

  int w = threadIdx.x >> 6, lane = threadIdx.x & 63;
  int ln = lane & 15, quad = lane >> 4;
  int band = 31 - blockIdx.x;         // 128-row band
  int b = blockIdx.y, z = blockIdx.z; // batch, split-K sixth
  int q0 = band * 128;
  int qw = q0 + w * 32;               // this wave's first Q-row (owns 32 rows)

  const u16* qbb = qb + (size_t)b * 4096 * 64;
  const u16* kbb = kb + (size_t)b * 4096 * 64;
  const u16* vtb = vT + (size_t)b * 64 * 4096;

  short8 qf0a = *(const short8*)(qbb + (size_t)(qw + ln) * 64 + quad * 8);
  short8 qf1a = *(const short8*)(qbb + (size_t)(qw + ln) * 64 + 32 + quad * 8);
  short8 qf0b = *(const short8*)(qbb + (size_t)(qw + 16 + ln) * 64 + quad * 8);
  short8 qf1b = *(const short8*)(qbb + (size_t)(qw + 16 + ln) * 64 + 32 + quad * 8);

  short8 ones;
#pragma unroll
  for (int j = 0; j < 8; j++) ones[j] = (short)0x3F80;   // bf16 1.0

  fx4 oa[4], ob[4];
#pragma unroll
  for (int j = 0; j < 4; j++) { oa[j] = (fx4){0.f,0.f,0.f,0.f}; ob[j] = (fx4){0.f,0.f,0.f,0.f}; }
  float la[4] = {0.f,0.f,0.f,0.f}, lb[4] = {0.f,0.f,0.f,0.f};

  int n = 2 * band + 2;               // 64-key tiles this band needs
  int c = (n + 5) / 6;                // tiles per split-K sixth
  int lo = z * c; if (lo > n) lo = n;
  int hi = lo + c; if (hi > n) hi = n;

  int t0c = w * 64 + lane;
  if (lo < hi) {
#pragma unroll
    for (int j = 0; j < 2; j++) {
      int cc = t0c + j * 256;
      int row = cc >> 3, slot = cc & 7, sw_ = (slot ^ (row & 7)) * 8;
      async16(kbb + ((size_t)lo * 64 + row) * 64 + sw_, (char*)Kstg[0] + cc * 16);
      async16(vtb + (size_t)row * 4096 + lo * 64 + sw_, (char*)Vstg[0] + cc * 16);
    }
  }

  for (int t = lo; t < hi; t++) {
    __syncthreads();                  // publishes buf (t-lo)&1
    if (t + 1 < hi) {
      int nb = (t - lo + 1) & 1;
#pragma unroll
      for (int j = 0; j < 2; j++) {
        int cc = t0c + j * 256;
        int row = cc >> 3, slot = cc & 7, sw_ = (slot ^ (row & 7)) * 8;
        async16(kbb + ((size_t)(t + 1) * 64 + row) * 64 + sw_, (char*)Kstg[nb] + cc * 16);
        async16(vtb + (size_t)row * 4096 + (t + 1) * 64 + sw_, (char*)Vstg[nb] + cc * 16);
      }
    }
    if (64 * t > qw + 31) continue;   // tile entirely above this wave's rows

    const u16* Kb = Kstg[(t - lo) & 1];
    const u16* Vb = Vstg[(t - lo) & 1];

    fx4 sAa[4], sAb[4];
#pragma unroll
    for (int nt = 0; nt < 4; nt++) {
      int row = nt * 16 + ln;
      int s0_ = quad ^ (row & 7), s1_ = (quad + 4) ^ (row & 7);
      short8 kf0 = *(const short8*)(Kb + (row * 8 + s0_) * 8);
      short8 kf1 = *(const short8*)(Kb + (row * 8 + s1_) * 8);
      sAa[nt] = mfma16(qf0a, kf0, (fx4){0.f,0.f,0.f,0.f});
      sAa[nt] = mfma16(qf1a, kf1, sAa[nt]);
      sAb[nt] = mfma16(qf0b, kf0, (fx4){0.f,0.f,0.f,0.f});
      sAb[nt] = mfma16(qf1b, kf1, sAb[nt]);
    }

    if (64 * t + 63 > qw) {
#pragma unroll
      for (int nt = 0; nt < 4; nt++)
#pragma unroll
        for (int reg = 0; reg < 4; reg++) {
          int col = t * 64 + nt * 16 + ln;
          int ra = qw + quad * 4 + reg;
          if (col > ra) sAa[nt][reg] = -1e30f;
          if (col > ra + 16) sAb[nt][reg] = -1e30f;
        }
    }

#pragma unroll
    for (int nt = 0; nt < 4; nt++)
#pragma unroll
      for (int reg = 0; reg < 4; reg++) {
        Ps[w][(quad * 4 + reg) * 72 + nt * 16 + ln] =
            p2bf(__builtin_amdgcn_exp2f(sAa[nt][reg]));
        Ps[w][(16 + quad * 4 + reg) * 72 + nt * 16 + ln] =
            p2bf(__builtin_amdgcn_exp2f(sAb[nt][reg]));
      }

    short8 pf0a = *(const short8*)(&Ps[w][ln * 72 + quad * 8]);
    short8 pf1a = *(const short8*)(&Ps[w][ln * 72 + 32 + quad * 8]);
    short8 pf0b = *(const short8*)(&Ps[w][(16 + ln) * 72 + quad * 8]);
    short8 pf1b = *(const short8*)(&Ps[w][(16 + ln) * 72 + 32 + quad * 8]);

    fx4 lacc = mfma16(pf0a, ones, (fx4){0.f,0.f,0.f,0.f});
    lacc = mfma16(pf1a, ones, lacc);
#pragma unroll
    for (int reg = 0; reg < 4; reg++) la[reg] += lacc[reg];
    lacc = mfma16(pf0b, ones, (fx4){0.f,0.f,0.f,0.f});
    lacc = mfma16(pf1b, ones, lacc);
#pragma unroll
    for (int reg = 0; reg < 4; reg++) lb[reg] += lacc[reg];

#pragma unroll
    for (int nt2 = 0; nt2 < 4; nt2++) {
      int row = nt2 * 16 + ln;
      int s0_ = quad ^ (row & 7), s1_ = (quad + 4) ^ (row & 7);
      short8 vf0 = *(const short8*)(Vb + (row * 8 + s0_) * 8);
      short8 vf1 = *(const short8*)(Vb + (row * 8 + s1_) * 8);
      oa[nt2] = mfma16(pf0a, vf0, oa[nt2]);
      oa[nt2] = mfma16(pf1a, vf1, oa[nt2]);
      ob[nt2] = mfma16(pf0b, vf0, ob[nt2]);
      ob[nt2] = mfma16(pf1b, vf1, ob[nt2]);
    }
  }

  // write unnormalized BF16 partials + fp32 l; each wave owns its 32 rows
  u16* dst = pob + (size_t)z * (4 * 4096 * 64);
#pragma unroll
  for (int nt2 = 0; nt2 < 4; nt2++)
#pragma unroll
    for (int reg = 0; reg < 4; reg++) {
      int ra = qw + quad * 4 + reg;
      dst[((size_t)b * 4096 + ra) * 64 + nt2 * 16 + ln] = p2bf(oa[nt2][reg]);
      dst[((size_t)b * 4096 + ra + 16) * 64 + nt2 * 16 + ln] = p2bf(ob[nt2][reg]);
    }
  if (ln == 0) {
#pragma unroll
    for (int reg = 0; reg < 4; reg++) {
      int ra = qw + quad * 4 + reg;
      mlb[((size_t)z * 4 + b) * 4096 + ra] = la[reg];
      mlb[((size_t)z * 4 + b) * 4096 + ra + 16] = lb[reg];
    }
  }
}

// ---------------- merge the six split-K parts (bf16 partials): out = Σo_z / Σl_z
__global__ __launch_bounds__(256) void merge_kernel(float* __restrict__ out,
                                                    const u16* __restrict__ pob,
                                                    const float* __restrict__ mlb) {
  int qt = blockIdx.x, b = blockIdx.y;
  int r = threadIdx.x >> 3;
  int c = (threadIdx.x & 7) * 8;
  size_t row = (size_t)b * 4096 + qt * 32 + r;
  float l = 0.f;
#pragma unroll
  for (int z = 0; z < 6; z++) l += mlb[(size_t)z * 4 * 4096 + row];
  float inv = 1.0f / l;
  float acc[8];
#pragma unroll
  for (int j = 0; j < 8; j++) acc[j] = 0.f;
#pragma unroll
  for (int z = 0; z < 6; z++) {
    const u16* pp = pob + (size_t)z * (4 * 4096 * 64) + row * 64 + c;
    u16x8 v = *(const u16x8*)pp;
#pragma unroll
    for (int j = 0; j < 8; j++) acc[j] += bf2f(v[j]);
  }
  float* op = out + row * 64 + c;
#pragma unroll
  for (int j = 0; j < 8; j++) op[j] = acc[j] * inv;
}

extern "C" void kernel_launch(void* const* d_in, const int* in_sizes, int n_in,
                              void* d_out, int out_size, void* d_ws, size_t ws_size,
                              hipStream_t stream) {
  const float* x  = (const float*)d_in[0];
  const float* Wq = (const float*)d_in[1];
  const float* Wk = (const float*)d_in[2];
  const float* Wv = (const float*)d_in[3];

  u16* qbw = (u16*)d_ws;                          // [16384][64] bf16, 2MB
  u16* kbw = qbw + (size_t)TOKENS * 64;           // 2MB
  u16* vtw = kbw + (size_t)TOKENS * 64;           // 2MB
  u16* wfr = vtw + (size_t)TOKENS * 64;           // 288KB
  u16* pob = wfr + (size_t)3 * KSTEPS * 256 * 8;  // [6][4][4096][64] bf16, 12MB
  float* mlb = (float*)(pob + (size_t)6 * 4 * 4096 * 64);  // [6][4][4096] fp32

  prep_w_kernel<<<72, 256, 0, stream>>>(Wq, Wk, Wv, wfr);
  proj_kernel<<<TOKENS / 64, 256, 0, stream>>>(x, wfr, qbw, kbw, vtw);
  attn_kernel<<<dim3(32, 4, 6), 256, 0, stream>>>(qbw, kbw, vtw, pob, mlb);
  merge_kernel<<<dim3(128, 4), 256, 0, stream>>>((float*)d_out, pob, mlb);
}

// Round 18
// 127.797 us; speedup vs baseline: 1.0462x; 1.0462x over previous
//
#include <hip/hip_runtime.h>
#include <stdint.h>

#define KSTEPS 24              // 768 / 32
#define TOKENS 16384           // B*S

typedef short short8 __attribute__((ext_vector_type(8)));
typedef float fx4 __attribute__((ext_vector_type(4)));
typedef unsigned short u16;
typedef u16 u16x4 __attribute__((ext_vector_type(4)));
typedef u16 u16x8 __attribute__((ext_vector_type(8)));

static __device__ __forceinline__ u16 f2bf(float f) {
  union { float f; unsigned u; } v; v.f = f;
  return (u16)((v.u + 0x7fffu + ((v.u >> 16) & 1u)) >> 16);
}

// cheap round (half-up): used post-exp2 / on partials, tolerance-safe
static __device__ __forceinline__ u16 p2bf(float f) {
  union { float f; unsigned u; } v; v.f = f;
  return (u16)((v.u + 0x8000u) >> 16);
}

static __device__ __forceinline__ float bf2f(u16 h) {
  union { unsigned u; float f; } v; v.u = ((unsigned)h) << 16;
  return v.f;
}

static __device__ __forceinline__ fx4 mfma16(short8 a, short8 b, fx4 c) {
  return __builtin_amdgcn_mfma_f32_16x16x32_bf16(a, b, c, 0, 0, 0);
}

// async global->LDS, 16B/lane; lds dest = wave-uniform base + lane*16
static __device__ __forceinline__ void async16(const void* g, void* l) {
  __builtin_amdgcn_global_load_lds(
      (const __attribute__((address_space(1))) void*)g,
      (__attribute__((address_space(3))) void*)(unsigned int)(uintptr_t)l,
      16, 0, 0);
}

// ---------------- prep: W[768][64] fp32 (q,k,v) -> bf16 pre-fragmented B-operand layout
__global__ void prep_w_kernel(const float* __restrict__ Wq, const float* __restrict__ Wk,
                              const float* __restrict__ Wv, u16* __restrict__ wfrag) {
  int idx  = blockIdx.x * 256 + threadIdx.x;   // 72*256 = 18432 = 3*24*4*64
  int lane = idx & 63;
  int fid  = idx >> 6;
  int nt   = fid & 3;
  int ks   = (fid >> 2) % KSTEPS;
  int mat  = fid / (KSTEPS * 4);
  const float* W = (mat == 0) ? Wq : (mat == 1) ? Wk : Wv;
  int n  = nt * 16 + (lane & 15);
  int k0 = ks * 32 + (lane >> 4) * 8;
  short8 out;
#pragma unroll
  for (int j = 0; j < 8; j++) out[j] = (short)f2bf(W[(size_t)(k0 + j) * 64 + n]);
  *(short8*)(wfrag + (size_t)idx * 8) = out;
}

// ---------------- projection GEMM v5 (r16's — best measured): LDS-staged,
// BK=64: 12 barrier rounds, 2 ksteps & 12 MFMAs/wave per round.
// 32 tok/block, 256 thr, 4 waves = 2 row-halves x 2 col-halves.
__global__ __launch_bounds__(256) void proj_kernel(const float* __restrict__ x,
                                                   const u16* __restrict__ wfrag,
                                                   u16* __restrict__ qb,
                                                   u16* __restrict__ kb,
                                                   u16* __restrict__ vT) {
  __shared__ float xs[2][32 * 64];    // [dbuf][tok][64 floats] chunk-swizzled, 8KB
  __shared__ u16  Ws[2][24 * 512];    // [dbuf][kk*12 + f][lane][8], 24KB

  int w = threadIdx.x >> 6, lane = threadIdx.x & 63;
  int ln = lane & 15, quad = lane >> 4;
  int rw = w >> 1, cs = w & 1;
  int s0 = blockIdx.x * 32;

  fx4 acc[6];
#pragma unroll
  for (int j = 0; j < 6; j++) acc[j] = (fx4){0.f, 0.f, 0.f, 0.f};

#define STAGE_X(rnd, buf)                                                      \
  {                                                                            \
    _Pragma("unroll")                                                          \
    for (int j = 0; j < 2; j++) {                                              \
      int cc = (w * 2 + j) * 64 + lane;                                        \
      int row = cc >> 4, c = cc & 15;                                          \
      int sc = (c & 8) | ((c ^ row) & 7);                                      \
      async16(x + (size_t)(s0 + row) * 768 + (rnd) * 64 + sc * 4,              \
              (char*)xs[buf] + (w * 2 + j) * 1024);                            \
    }                                                                          \
  }
#define STAGE_W(rnd, buf)                                                      \
  {                                                                            \
    _Pragma("unroll")                                                          \
    for (int m = 0; m < 3; m++)                                                \
      _Pragma("unroll")                                                        \
      for (int kk = 0; kk < 2; kk++)                                           \
        async16(wfrag + ((size_t)(m * KSTEPS + (rnd) * 2 + kk) * 256 +         \
                         w * 64 + lane) * 8,                                   \
                (char*)Ws[buf] + (kk * 12 + m * 4 + w) * 1024 + lane * 16);    \
  }

  STAGE_X(0, 0);
  STAGE_W(0, 0);

  int r = rw * 16 + ln;               // A-frag token row for this lane
  for (int rnd = 0; rnd < 12; rnd++) {
    __syncthreads();                  // publishes buf rnd&1
    if (rnd < 11) {
      STAGE_X(rnd + 1, (rnd + 1) & 1);
      STAGE_W(rnd + 1, (rnd + 1) & 1);
    }
    const float* xb = xs[rnd & 1];
    const u16*  wb = Ws[rnd & 1];
#pragma unroll
    for (int kk = 0; kk < 2; kk++) {
      int c0 = kk * 8 + 2 * quad;
      int sl0 = (c0 & 8) | ((c0 ^ r) & 7);
      int sl1 = ((c0 + 1) & 8) | (((c0 + 1) ^ r) & 7);
      fx4 xa = *(const fx4*)(xb + r * 64 + sl0 * 4);
      fx4 xv = *(const fx4*)(xb + r * 64 + sl1 * 4);
      short8 af;
#pragma unroll
      for (int j = 0; j < 4; j++) { af[j] = (short)f2bf(xa[j]); af[4 + j] = (short)f2bf(xv[j]); }
#pragma unroll
      for (int j = 0; j < 6; j++) {
        short8 bf = *(const short8*)(wb + (kk * 12 + cs * 6 + j) * 512 + lane * 8);
        acc[j] = mfma16(af, bf, acc[j]);
      }
    }
  }
#undef STAGE_X
#undef STAGE_W

  // epilogue: C/D layout col = lane&15, row = quad*4 + reg
  int tok0 = s0 + rw * 16 + quad * 4;
#pragma unroll
  for (int j = 0; j < 6; j++) {
    int f = cs * 6 + j;
    int d = (f & 3) * 16 + ln;
    if (f < 4) {
      // Q pre-scaled by 0.125 * log2(e): scores land in exp2 domain
#pragma unroll
      for (int reg = 0; reg < 4; reg++)
        qb[(size_t)(tok0 + reg) * 64 + d] = f2bf(acc[j][reg] * 0.180336887f);
    } else if (f < 8) {
#pragma unroll
      for (int reg = 0; reg < 4; reg++)
        kb[(size_t)(tok0 + reg) * 64 + d] = f2bf(acc[j][reg]);
    } else {
      int b = tok0 >> 12, s = tok0 & 4095;
      u16x4 vp;
#pragma unroll
      for (int reg = 0; reg < 4; reg++) vp[reg] = f2bf(acc[j][reg]);
      *(u16x4*)(vT + ((size_t)b * 64 + d) * 4096 + s) = vp;
    }
  }
}

// ---------------- flash attention v9b: 32 Q-rows/wave, K+V DMA-staged dbuf,
// split-K 6-way; partials written as BF16 (halves merge traffic).
__global__ __launch_bounds__(256, 3) void attn_kernel(const u16* __restrict__ qb,
                                                      const u16* __restrict__ kb,
                                                      const u16* __restrict__ vT,
                                                      u16* __restrict__ pob,
                                                      float* __restrict__ mlb) {
  __shared__ u16 Kstg[2][4096];       // [buf][64 keys x 64 d]   16KB
  __shared__ u16 Vstg[2][4096];       // [buf][64 d x 64 keys]   16KB (V^T)
  __shared__ u16 Ps[4][32 * 72];      // per-wave P (32 rows), padded: 18KB

  int w = threadIdx.x >> 6, lane = threadIdx.x & 63;
  int ln = lane & 15, quad = lane >> 4;
  int band = 31 - blockIdx.x;         // 128-row band
  int b = blockIdx.y, z = blockIdx.z; // batch, split-K sixth
  int q0 = band * 128;
  int qw = q0 + w * 32;               // this wave's first Q-row (owns 32 rows)

  const u16* qbb = qb + (size_t)b * 4096 * 64;
  const u16* kbb = kb + (size_t)b * 4096 * 64;
  const u16* vtb = vT + (size_t)b * 64 * 4096;

  short8 qf0a = *(const short8*)(qbb + (size_t)(qw + ln) * 64 + quad * 8);
  short8 qf1a = *(const short8*)(qbb + (size_t)(qw + ln) * 64 + 32 + quad * 8);
  short8 qf0b = *(const short8*)(qbb + (size_t)(qw + 16 + ln) * 64 + quad * 8);
  short8 qf1b = *(const short8*)(qbb + (size_t)(qw + 16 + ln) * 64 + 32 + quad * 8);

  short8 ones;
#pragma unroll
  for (int j = 0; j < 8; j++) ones[j] = (short)0x3F80;   // bf16 1.0

  fx4 oa[4], ob[4];
#pragma unroll
  for (int j = 0; j < 4; j++) { oa[j] = (fx4){0.f,0.f,0.f,0.f}; ob[j] = (fx4){0.f,0.f,0.f,0.f}; }
  float la[4] = {0.f,0.f,0.f,0.f}, lb[4] = {0.f,0.f,0.f,0.f};

  int n = 2 * band + 2;               // 64-key tiles this band needs
  int c = (n + 5) / 6;                // tiles per split-K sixth
  int lo = z * c; if (lo > n) lo = n;
  int hi = lo + c; if (hi > n) hi = n;

  int t0c = w * 64 + lane;
  if (lo < hi) {
#pragma unroll
    for (int j = 0; j < 2; j++) {
      int cc = t0c + j * 256;
      int row = cc >> 3, slot = cc & 7, sw_ = (slot ^ (row & 7)) * 8;
      async16(kbb + ((size_t)lo * 64 + row) * 64 + sw_, (char*)Kstg[0] + cc * 16);
      async16(vtb + (size_t)row * 4096 + lo * 64 + sw_, (char*)Vstg[0] + cc * 16);
    }
  }

  for (int t = lo; t < hi; t++) {
    __syncthreads();                  // publishes buf (t-lo)&1
    if (t + 1 < hi) {
      int nb = (t - lo + 1) & 1;
#pragma unroll
      for (int j = 0; j < 2; j++) {
        int cc = t0c + j * 256;
        int row = cc >> 3, slot = cc & 7, sw_ = (slot ^ (row & 7)) * 8;
        async16(kbb + ((size_t)(t + 1) * 64 + row) * 64 + sw_, (char*)Kstg[nb] + cc * 16);
        async16(vtb + (size_t)row * 4096 + (t + 1) * 64 + sw_, (char*)Vstg[nb] + cc * 16);
      }
    }
    if (64 * t > qw + 31) continue;   // tile entirely above this wave's rows

    const u16* Kb = Kstg[(t - lo) & 1];
    const u16* Vb = Vstg[(t - lo) & 1];

    fx4 sAa[4], sAb[4];
#pragma unroll
    for (int nt = 0; nt < 4; nt++) {
      int row = nt * 16 + ln;
      int s0_ = quad ^ (row & 7), s1_ = (quad + 4) ^ (row & 7);
      short8 kf0 = *(const short8*)(Kb + (row * 8 + s0_) * 8);
      short8 kf1 = *(const short8*)(Kb + (row * 8 + s1_) * 8);
      sAa[nt] = mfma16(qf0a, kf0, (fx4){0.f,0.f,0.f,0.f});
      sAa[nt] = mfma16(qf1a, kf1, sAa[nt]);
      sAb[nt] = mfma16(qf0b, kf0, (fx4){0.f,0.f,0.f,0.f});
      sAb[nt] = mfma16(qf1b, kf1, sAb[nt]);
    }

    if (64 * t + 63 > qw) {
#pragma unroll
      for (int nt = 0; nt < 4; nt++)
#pragma unroll
        for (int reg = 0; reg < 4; reg++) {
          int col = t * 64 + nt * 16 + ln;
          int ra = qw + quad * 4 + reg;
          if (col > ra) sAa[nt][reg] = -1e30f;
          if (col > ra + 16) sAb[nt][reg] = -1e30f;
        }
    }

#pragma unroll
    for (int nt = 0; nt < 4; nt++)
#pragma unroll
      for (int reg = 0; reg < 4; reg++) {
        Ps[w][(quad * 4 + reg) * 72 + nt * 16 + ln] =
            p2bf(__builtin_amdgcn_exp2f(sAa[nt][reg]));
        Ps[w][(16 + quad * 4 + reg) * 72 + nt * 16 + ln] =
            p2bf(__builtin_amdgcn_exp2f(sAb[nt][reg]));
      }

    short8 pf0a = *(const short8*)(&Ps[w][ln * 72 + quad * 8]);
    short8 pf1a = *(const short8*)(&Ps[w][ln * 72 + 32 + quad * 8]);
    short8 pf0b = *(const short8*)(&Ps[w][(16 + ln) * 72 + quad * 8]);
    short8 pf1b = *(const short8*)(&Ps[w][(16 + ln) * 72 + 32 + quad * 8]);

    fx4 lacc = mfma16(pf0a, ones, (fx4){0.f,0.f,0.f,0.f});
    lacc = mfma16(pf1a, ones, lacc);
#pragma unroll
    for (int reg = 0; reg < 4; reg++) la[reg] += lacc[reg];
    lacc = mfma16(pf0b, ones, (fx4){0.f,0.f,0.f,0.f});
    lacc = mfma16(pf1b, ones, lacc);
#pragma unroll
    for (int reg = 0; reg < 4; reg++) lb[reg] += lacc[reg];

#pragma unroll
    for (int nt2 = 0; nt2 < 4; nt2++) {
      int row = nt2 * 16 + ln;
      int s0_ = quad ^ (row & 7), s1_ = (quad + 4) ^ (row & 7);
      short8 vf0 = *(const short8*)(Vb + (row * 8 + s0_) * 8);
      short8 vf1 = *(const short8*)(Vb + (row * 8 + s1_) * 8);
      oa[nt2] = mfma16(pf0a, vf0, oa[nt2]);
      oa[nt2] = mfma16(pf1a, vf1, oa[nt2]);
      ob[nt2] = mfma16(pf0b, vf0, ob[nt2]);
      ob[nt2] = mfma16(pf1b, vf1, ob[nt2]);
    }
  }

  // write unnormalized BF16 partials + fp32 l; each wave owns its 32 rows
  u16* dst = pob + (size_t)z * (4 * 4096 * 64);
#pragma unroll
  for (int nt2 = 0; nt2 < 4; nt2++)
#pragma unroll
    for (int reg = 0; reg < 4; reg++) {
      int ra = qw + quad * 4 + reg;
      dst[((size_t)b * 4096 + ra) * 64 + nt2 * 16 + ln] = p2bf(oa[nt2][reg]);
      dst[((size_t)b * 4096 + ra + 16) * 64 + nt2 * 16 + ln] = p2bf(ob[nt2][reg]);
    }
  if (ln == 0) {
#pragma unroll
    for (int reg = 0; reg < 4; reg++) {
      int ra = qw + quad * 4 + reg;
      mlb[((size_t)z * 4 + b) * 4096 + ra] = la[reg];
      mlb[((size_t)z * 4 + b) * 4096 + ra + 16] = lb[reg];
    }
  }
}

// ---------------- merge the six split-K parts (bf16 partials): out = Σo_z / Σl_z
__global__ __launch_bounds__(256) void merge_kernel(float* __restrict__ out,
                                                    const u16* __restrict__ pob,
                                                    const float* __restrict__ mlb) {
  int qt = blockIdx.x, b = blockIdx.y;
  int r = threadIdx.x >> 3;
  int c = (threadIdx.x & 7) * 8;
  size_t row = (size_t)b * 4096 + qt * 32 + r;
  float l = 0.f;
#pragma unroll
  for (int z = 0; z < 6; z++) l += mlb[(size_t)z * 4 * 4096 + row];
  float inv = 1.0f / l;
  float acc[8];
#pragma unroll
  for (int j = 0; j < 8; j++) acc[j] = 0.f;
#pragma unroll
  for (int z = 0; z < 6; z++) {
    const u16* pp = pob + (size_t)z * (4 * 4096 * 64) + row * 64 + c;
    u16x8 v = *(const u16x8*)pp;
#pragma unroll
    for (int j = 0; j < 8; j++) acc[j] += bf2f(v[j]);
  }
  float* op = out + row * 64 + c;
#pragma unroll
  for (int j = 0; j < 8; j++) op[j] = acc[j] * inv;
}

extern "C" void kernel_launch(void* const* d_in, const int* in_sizes, int n_in,
                              void* d_out, int out_size, void* d_ws, size_t ws_size,
                              hipStream_t stream) {
  const float* x  = (const float*)d_in[0];
  const float* Wq = (const float*)d_in[1];
  const float* Wk = (const float*)d_in[2];
  const float* Wv = (const float*)d_in[3];

  u16* qbw = (u16*)d_ws;                          // [16384][64] bf16, 2MB
  u16* kbw = qbw + (size_t)TOKENS * 64;           // 2MB
  u16* vtw = kbw + (size_t)TOKENS * 64;           // 2MB
  u16* wfr = vtw + (size_t)TOKENS * 64;           // 288KB
  u16* pob = wfr + (size_t)3 * KSTEPS * 256 * 8;  // [6][4][4096][64] bf16, 12MB
  float* mlb = (float*)(pob + (size_t)6 * 4 * 4096 * 64);  // [6][4][4096] fp32

  prep_w_kernel<<<72, 256, 0, stream>>>(Wq, Wk, Wv, wfr);
  proj_kernel<<<TOKENS / 32, 256, 0, stream>>>(x, wfr, qbw, kbw, vtw);
  attn_kernel<<<dim3(32, 4, 6), 256, 0, stream>>>(qbw, kbw, vtw, pob, mlb);
  merge_kernel<<<dim3(128, 4), 256, 0, stream>>>((float*)d_out, pob, mlb);
}